// Round 8
// baseline (193.198 us; speedup 1.0000x reference)
//
#include <hip/hip_runtime.h>

#define NS 4096
#define DC 32
#define MAXIT2 104   // cap: 104 double-rounds = 208 rounds ~= 13.9 sweeps
#define CHKIV 8      // gate check every 8 double-rounds (16 rounds)

typedef float v2f __attribute__((ext_vector_type(2)));

static __device__ __forceinline__ v2f vswap(v2f b) {
    return __builtin_shufflevector(b, b, 1, 0);
}

// ---------------------------------------------------------------------------
// P1 (R1-verbatim) + d_out zeroing: W_d = A_d A_d^H, S_d = A_d + A_d^H,
// column sums of A and A^2.
// ---------------------------------------------------------------------------
__global__ __launch_bounds__(256) void precompute_kernel(
    const float* __restrict__ Ar, const float* __restrict__ Ai,
    float2* __restrict__ S, float2* __restrict__ W,
    float2* __restrict__ cA, float2* __restrict__ cA2,
    float* __restrict__ out)
{
    const int d = blockIdx.x;
    const int t = threadIdx.x;
    if (d == 0 && t == 0) out[0] = 0.f;          // replaces memset launch
    const int i = t >> 4, j = t & 15;
    __shared__ float ar[16][16], ai[16][16], a2r[16][16], a2i[16][16];
    ar[i][j] = Ar[d*256 + t];
    ai[i][j] = Ai[d*256 + t];
    __syncthreads();
    float a2re = 0.f, a2im = 0.f, wre = 0.f, wim = 0.f;
    for (int k = 0; k < 16; ++k) {
        float xr = ar[i][k], xi = ai[i][k];
        a2re += xr*ar[k][j] - xi*ai[k][j];
        a2im += xr*ai[k][j] + xi*ar[k][j];
        wre += xr*ar[j][k] + xi*ai[j][k];
        wim += xi*ar[j][k] - xr*ai[j][k];
    }
    S[d*256 + t] = make_float2(ar[i][j] + ar[j][i], ai[i][j] - ai[j][i]);
    W[d*256 + t] = make_float2(wre, wim);
    a2r[i][j] = a2re; a2i[i][j] = a2im;
    __syncthreads();
    if (t < 16) {
        float sr = 0.f, si = 0.f, s2r = 0.f, s2i = 0.f;
        for (int ii = 0; ii < 16; ++ii) {
            sr  += ar[ii][t];  si  += ai[ii][t];
            s2r += a2r[ii][t]; s2i += a2i[ii][t];
        }
        cA [d*16 + t] = make_float2(sr,  si);
        cA2[d*16 + t] = make_float2(s2r, s2i);
    }
}

// ---------------------------------------------------------------------------
// Fused cyclic Jacobi, TWO samples per 64-lane wave (interleaved streams).
// Per sample: packed-f32 math, register-resident own elements, XOR-swizzled
// byte-addressed LDS, sweep-level convergence gate (pair exits when both
// converged). Lane t: row i = t>>2, cols jb..jb+3 for BOTH samples.
// ---------------------------------------------------------------------------
__global__ __launch_bounds__(64) void energy_kernel(
    const float* __restrict__ X,
    const float2* __restrict__ S, const float2* __restrict__ W,
    const float2* __restrict__ cA, const float2* __restrict__ cA2,
    float* __restrict__ out)
{
    const int nA = 2*blockIdx.x, nB = nA + 1;
    const int t = threadIdx.x;
    const int i  = t >> 2;
    const int jb = (t & 3) * 4;

    // sample s data at byte offset s*2048 within each array
    __shared__ v2f    Ha[512], Hb[512], Va[512], Vb[512];
    __shared__ float4 csco[32];     // [s*16 + c]
    __shared__ int    prtI[8];      // [s*4 + w]: packed bytes partner<<3
    __shared__ float  xS[2][32];
    __shared__ float  diagS[2][16];
    __shared__ v2f    psiS[2][16];
    __shared__ int    midxS[2];

    const float* XnA = X + nA*DC;
    const float* XnB = X + nB*DC;
    { int s = t >> 5, d = t & 31; xS[s][d] = X[(nA + s)*DC + d]; }

    const int i7 = i << 7, i3 = i << 3;
    const int shi = (i & 3) * 8;
    int amB[4], j3[4];
    #pragma unroll
    for (int u = 0; u < 4; ++u) {
        amB[u] = i7 | (((jb + u) ^ i) << 3);
        j3[u]  = (jb + u) << 3;
    }

    // ---- build both H's; W/S loads shared ----
    v2f hA[4], hB[4], vA[4], vB[4];
    float tolA, tolB;
    {
        const int e0 = t*4;
        v2f aA[4] = {{0.f,0.f},{0.f,0.f},{0.f,0.f},{0.f,0.f}};
        v2f aB[4] = {{0.f,0.f},{0.f,0.f},{0.f,0.f},{0.f,0.f}};
        float sxA = 0.f, sxB = 0.f;
        for (int d = 0; d < DC; ++d) {
            float xa = XnA[d], xb = XnB[d];
            sxA += xa*xa; sxB += xb*xb;
            const float4* w4 = (const float4*)(W + d*256 + e0);
            const float4* s4 = (const float4*)(S + d*256 + e0);
            float4 wa = w4[0], wb = w4[1];
            float4 sa = s4[0], sb = s4[1];
            v2f xva = {xa, xa}, xvb = {xb, xb};
            v2f w0 = {wa.x, wa.y}, w1 = {wa.z, wa.w};
            v2f w2 = {wb.x, wb.y}, w3 = {wb.z, wb.w};
            v2f s0 = {sa.x, sa.y}, s1 = {sa.z, sa.w};
            v2f s2 = {sb.x, sb.y}, s3 = {sb.z, sb.w};
            aA[0] += w0 - xva*s0; aB[0] += w0 - xvb*s0;
            aA[1] += w1 - xva*s1; aB[1] += w1 - xvb*s1;
            aA[2] += w2 - xva*s2; aB[2] += w2 - xvb*s2;
            aA[3] += w3 - xva*s3; aB[3] += w3 - xvb*s3;
        }
        float sdA = 0.5f*sxA + 1e-5f, sdB = 0.5f*sxB + 1e-5f;
        v2f nf = {0.f, 0.f};
        #pragma unroll
        for (int u = 0; u < 4; ++u) {
            int j = jb + u;
            v2f ha = 0.5f * aA[u], hb = 0.5f * aB[u];
            v2f vi = (i == j) ? (v2f){1.f, 0.f} : (v2f){0.f, 0.f};
            if (i == j) { ha.x += sdA; hb.x += sdB; }
            hA[u] = ha; hB[u] = hb; vA[u] = vi; vB[u] = vi;
            nf.x += ha.x*ha.x + ha.y*ha.y;
            nf.y += hb.x*hb.x + hb.y*hb.y;
            *(v2f*)((char*)Ha + amB[u])        = ha;
            *(v2f*)((char*)Ha + amB[u] + 2048) = hb;
            *(v2f*)((char*)Va + amB[u])        = vi;
            *(v2f*)((char*)Va + amB[u] + 2048) = vi;
        }
        #pragma unroll
        for (int m = 1; m < 64; m <<= 1) {
            nf.x += __shfl_xor(nf.x, m);
            nf.y += __shfl_xor(nf.y, m);
        }
        tolA = 1e-10f * nf.x; tolB = 1e-10f * nf.y;
    }
    __syncthreads();

    int rr = 0;

    // pivot for both samples: lanes 0..7 -> A, 8..15 -> B
    auto pivot = [&](const v2f* hc) {
        if (t < 16) {
            const int s = t >> 3, tt = t & 7;
            const char* base = (const char*)hc + (s << 11);
            int p, q;
            if (tt == 0) { p = 15; q = rr; }
            else {
                p = rr + tt;      if (p >= 15) p -= 15;
                q = rr + 15 - tt; if (q >= 15) q -= 15;
            }
            float a  = (*(const v2f*)(base + (p << 7))).x;
            float dd = (*(const v2f*)(base + (q << 7))).x;
            v2f   b  = *(const v2f*)(base + ((p << 7) | ((q ^ p) << 3)));
            float ab2 = b.x*b.x + b.y*b.y;
            float c_, s_, er, ei;
            if (ab2 > 1e-60f) {
                float abr = __builtin_amdgcn_rsqf(ab2);
                er = b.x * abr; ei = b.y * abr;
                float tau = (dd - a) * (0.5f * abr);
                float den = fabsf(tau) + sqrtf(1.f + tau*tau);
                float tv = __builtin_amdgcn_rcpf(den);
                tv = (tau < 0.f) ? -tv : tv;
                c_ = __builtin_amdgcn_rsqf(1.f + tv*tv);
                s_ = tv * c_;
            } else { c_ = 1.f; s_ = 0.f; er = 1.f; ei = 0.f; }
            csco[s*16 + p] = make_float4(c_, 0.f, -s_*er, s_*ei);
            csco[s*16 + q] = make_float4(c_*er, -c_*ei, s_, 0.f);
            unsigned char* pb = (unsigned char*)prtI + s*16;
            pb[p] = (unsigned char)(q << 3);
            pb[q] = (unsigned char)(p << 3);
        }
    };

    // one sample's fused round; sb = sample byte offset (0 or 2048)
    auto body = [&](int sb, const v2f* hc, v2f* hn, const v2f* vc, v2f* vn,
                    v2f* h, v2f* v, const float4* cscoS, const int* prtS,
                    bool wantOff) -> float {
        float4 fi = cscoS[i];
        v2f cix = {fi.x, fi.x}, cir = {fi.y, -fi.y};
        v2f kix = {fi.z, fi.z}, kir = {fi.w, -fi.w};
        const int pib = (prtS[i >> 2] >> shi) & 255;
        const int pi7 = pib << 4;
        const int wj  = prtS[t & 3];
        const char* hcB = (const char*)hc + sb;
        const char* vcB = (const char*)vc + sb;
        char* hnB = (char*)hn + sb;
        char* vnB = (char*)vn + sb;
        float off2 = 0.f;
        #pragma unroll
        for (int u = 0; u < 4; ++u) {
            float4 fj = cscoS[jb + u];
            v2f cjx = {fj.x, fj.x}, cjr = {-fj.y, fj.y};
            v2f kjx = {fj.z, fj.z}, kjr = {-fj.w, fj.w};
            const int pj3 = (wj >> (8*u)) & 255;
            const int aipj  = i7  | (pj3   ^ i3);
            const int apij  = pi7 | (j3[u] ^ pib);
            const int apipj = pi7 | (pj3   ^ pib);

            v2f hij   = h[u];
            v2f hipj  = *(const v2f*)(hcB + aipj);
            v2f hpij  = *(const v2f*)(hcB + apij);
            v2f hpipj = *(const v2f*)(hcB + apipj);

            v2f top = cjx*hij  + cjr*vswap(hij)  + kjx*hipj  + kjr*vswap(hipj);
            v2f bot = cjx*hpij + cjr*vswap(hpij) + kjx*hpipj + kjr*vswap(hpipj);
            v2f res = cix*top  + cir*vswap(top)  + kix*bot   + kir*vswap(bot);
            h[u] = res;
            *(v2f*)(hnB + amB[u]) = res;
            if (wantOff && (jb + u) != i) off2 += res.x*res.x + res.y*res.y;

            v2f vipj = *(const v2f*)(vcB + aipj);
            v2f vres = cjx*v[u] + cjr*vswap(v[u]) + kjx*vipj + kjr*vswap(vipj);
            v[u] = vres;
            *(v2f*)(vnB + amB[u]) = vres;
        }
        return off2;
    };

    // ---- gated double-round loop (pair exits when BOTH converged) ----
    int iter = 0, chkcd = CHKIV;
    for (;;) {
        const bool chk = (chkcd == 1);
        pivot(Ha);
        __syncthreads();
        body(0,    Ha, Hb, Va, Vb, hA, vA, csco,      prtI,     false);
        body(2048, Ha, Hb, Va, Vb, hB, vB, csco + 16, prtI + 4, false);
        __syncthreads();
        rr = (rr == 14) ? 0 : rr + 1;
        pivot(Hb);
        __syncthreads();
        float oA = body(0,    Hb, Ha, Vb, Va, hA, vA, csco,      prtI,     chk);
        float oB = body(2048, Hb, Ha, Vb, Va, hB, vB, csco + 16, prtI + 4, chk);
        __syncthreads();
        rr = (rr == 14) ? 0 : rr + 1;
        ++iter;
        if (chk) {
            #pragma unroll
            for (int m = 1; m < 64; m <<= 1) {
                oA += __shfl_xor(oA, m);
                oB += __shfl_xor(oB, m);
            }
            if ((oA < tolA && oB < tolB) || iter >= MAXIT2) break;
            chkcd = CHKIV;
        } else --chkcd;
    }
    // even round count -> final H in Ha, V in Va

    // ---- per-sample diag argmin + eigvec extraction ----
    if (t < 32) {
        int s = t >> 4, m = t & 15;
        diagS[s][m] = (*(const v2f*)((const char*)Ha + (s << 11) + (m << 7))).x;
    }
    __syncthreads();
    if (t < 2) {
        float best = diagS[t][0]; int bi_ = 0;
        for (int m = 1; m < 16; ++m) {
            float vv = diagS[t][m];
            if (vv < best) { best = vv; bi_ = m; }
        }
        midxS[t] = bi_;
    }
    __syncthreads();
    if (t < 32) {
        int s = t >> 4, m = t & 15;
        int mi = midxS[s];
        psiS[s][m] = *(const v2f*)((const char*)Va + (s << 11)
                                   + (((m << 4) | (mi ^ m)) << 3));
    }
    __syncthreads();

    // ---- loss epilogue: lanes 0..31 -> sample A (d=t), 32..63 -> B ----
    float contrib;
    {
        const int s = t >> 5, d = t & 31;
        float tr = 0.f, ti = 0.f;
        v2f psi[16];
        for (int jj = 0; jj < 16; ++jj) {
            psi[jj] = psiS[s][jj];
            tr += psi[jj].x; ti += psi[jj].y;
        }
        float zr = 0.f, zi = 0.f, z2r = 0.f, z2i = 0.f;
        for (int jj = 0; jj < 16; ++jj) {
            float2 cj  = cA [d*16 + jj];
            float2 c2j = cA2[d*16 + jj];
            zr  += cj.x*psi[jj].x  - cj.y*psi[jj].y;
            zi  += cj.x*psi[jj].y  + cj.y*psi[jj].x;
            z2r += c2j.x*psi[jj].x - c2j.y*psi[jj].y;
            z2i += c2j.x*psi[jj].y + c2j.y*psi[jj].x;
        }
        float pos = zr*tr + zi*ti;
        float e2  = z2r*tr + z2i*ti;
        float dx  = pos - xS[s][d];
        contrib = dx*dx + 0.1f*(e2 - pos*pos);
    }
    for (int off = 32; off > 0; off >>= 1)
        contrib += __shfl_down(contrib, off);
    if (t == 0) atomicAdd(out, contrib * (1.0f/(float)NS));
}

extern "C" void kernel_launch(void* const* d_in, const int* in_sizes, int n_in,
                              void* d_out, int out_size, void* d_ws, size_t ws_size,
                              hipStream_t stream)
{
    const float* A_real = (const float*)d_in[0];
    const float* A_imag = (const float*)d_in[1];
    const float* X      = (const float*)d_in[2];
    float* out = (float*)d_out;

    float2* S   = (float2*)d_ws;          // 32*256
    float2* W   = S  + DC*256;            // 32*256
    float2* cA  = W  + DC*256;            // 32*16
    float2* cA2 = cA + DC*16;             // 32*16
    (void)in_sizes; (void)n_in; (void)out_size; (void)ws_size;

    precompute_kernel<<<DC, 256, 0, stream>>>(A_real, A_imag, S, W, cA, cA2, out);
    energy_kernel<<<NS/2, 64, 0, stream>>>(X, S, W, cA, cA2, out);
}

// Round 9
// 167.971 us; speedup vs baseline: 1.1502x; 1.1502x over previous
//
#include <hip/hip_runtime.h>

#define NS 4096
#define DC 32
#define MAXROUND 208  // cap ~13.9 sweeps
#define CHKIV 16      // gate check every 16 rounds

typedef float v2f __attribute__((ext_vector_type(2)));

static __device__ __forceinline__ v2f vswap(v2f b) {
    return __builtin_shufflevector(b, b, 1, 0);
}

// ---------------------------------------------------------------------------
// P1 (R1-verbatim) + d_out zeroing.
// ---------------------------------------------------------------------------
__global__ __launch_bounds__(256) void precompute_kernel(
    const float* __restrict__ Ar, const float* __restrict__ Ai,
    float2* __restrict__ S, float2* __restrict__ W,
    float2* __restrict__ cA, float2* __restrict__ cA2,
    float* __restrict__ out)
{
    const int d = blockIdx.x;
    const int t = threadIdx.x;
    if (d == 0 && t == 0) out[0] = 0.f;
    const int i = t >> 4, j = t & 15;
    __shared__ float ar[16][16], ai[16][16], a2r[16][16], a2i[16][16];
    ar[i][j] = Ar[d*256 + t];
    ai[i][j] = Ai[d*256 + t];
    __syncthreads();
    float a2re = 0.f, a2im = 0.f, wre = 0.f, wim = 0.f;
    for (int k = 0; k < 16; ++k) {
        float xr = ar[i][k], xi = ai[i][k];
        a2re += xr*ar[k][j] - xi*ai[k][j];
        a2im += xr*ai[k][j] + xi*ar[k][j];
        wre += xr*ar[j][k] + xi*ai[j][k];
        wim += xi*ar[j][k] - xr*ai[j][k];
    }
    S[d*256 + t] = make_float2(ar[i][j] + ar[j][i], ai[i][j] - ai[j][i]);
    W[d*256 + t] = make_float2(wre, wim);
    a2r[i][j] = a2re; a2i[i][j] = a2im;
    __syncthreads();
    if (t < 16) {
        float sr = 0.f, si = 0.f, s2r = 0.f, s2i = 0.f;
        for (int ii = 0; ii < 16; ++ii) {
            sr  += ar[ii][t];  si  += ai[ii][t];
            s2r += a2r[ii][t]; s2i += a2i[ii][t];
        }
        cA [d*16 + t] = make_float2(sr,  si);
        cA2[d*16 + t] = make_float2(s2r, s2i);
    }
}

// ---------------------------------------------------------------------------
// Quartet-ownership cyclic Jacobi: round rr partitions rows and columns into
// the same 8 tournament pairs; lane (a,b) owns quartet {r1,r2}x{c1,c2} and
// applies the full row-and-column rotation in registers. In-place H/V.
// ---------------------------------------------------------------------------
__global__ __launch_bounds__(64) void energy_kernel(
    const float* __restrict__ X,
    const float2* __restrict__ S, const float2* __restrict__ W,
    const float2* __restrict__ cA, const float2* __restrict__ cA2,
    float* __restrict__ out)
{
    const int n = blockIdx.x;
    const int t = threadIdx.x;
    const int a = t >> 3, b = t & 7;

    __shared__ v2f    H[256], V[256];
    __shared__ float4 coefR[8];    // raw (c, s, er, ei) per pair
    __shared__ float  xS[32];
    __shared__ float  diagS[16];
    __shared__ v2f    psiS[16];
    __shared__ int    midxS;

    const float* Xn = X + n*DC;
    if (t < 32) xS[t] = Xn[t];

    // ---- build H (R1-exact arithmetic; R7 build mapping) ----
    float tol2;
    {
        const int bi = t >> 2;            // build row
        const int bj = (t & 3) * 4;       // build col base
        const int e0 = t*4;
        v2f acc[4] = {{0.f,0.f},{0.f,0.f},{0.f,0.f},{0.f,0.f}};
        float sx2 = 0.f;
        for (int d = 0; d < DC; ++d) {
            float xd = Xn[d];
            sx2 += xd*xd;
            const float4* w4 = (const float4*)(W + d*256 + e0);
            const float4* s4 = (const float4*)(S + d*256 + e0);
            float4 wa = w4[0], wb = w4[1];
            float4 sa = s4[0], sb = s4[1];
            v2f xv = {xd, xd};
            acc[0] += (v2f){wa.x, wa.y} - xv * (v2f){sa.x, sa.y};
            acc[1] += (v2f){wa.z, wa.w} - xv * (v2f){sa.z, sa.w};
            acc[2] += (v2f){wb.x, wb.y} - xv * (v2f){sb.x, sb.y};
            acc[3] += (v2f){wb.z, wb.w} - xv * (v2f){sb.z, sb.w};
        }
        float sdiag = 0.5f*sx2 + 1e-5f;
        float nf = 0.f;
        #pragma unroll
        for (int u = 0; u < 4; ++u) {
            int j = bj + u;
            v2f hv = 0.5f * acc[u];
            if (bi == j) hv.x += sdiag;
            nf += hv.x*hv.x + hv.y*hv.y;
            const int ad = (bi << 7) | ((j ^ bi) << 3);
            *(v2f*)((char*)H + ad) = hv;
            *(v2f*)((char*)V + ad) = (bi == j) ? (v2f){1.f, 0.f} : (v2f){0.f, 0.f};
        }
        #pragma unroll
        for (int m = 1; m < 64; m <<= 1) nf += __shfl_xor(nf, m);
        tol2 = 1e-10f * nf;
    }
    __syncthreads();

    // ---- gated in-place round loop ----
    int rr = 0, iter = 0, chkcd = CHKIV;
    const int va0 = 2*a, va1 = 2*a + 1;
    for (;;) {
        // pivot: lanes 0..7 compute rotation for pair t, publish raw coeffs
        if (t < 8) {
            int p, q;
            if (t == 0) { p = 15; q = rr; }
            else {
                p = rr + t;      if (p >= 15) p -= 15;
                q = rr + 15 - t; if (q >= 15) q -= 15;
            }
            float av = (*(const v2f*)((const char*)H + (p << 7))).x;
            float dv = (*(const v2f*)((const char*)H + (q << 7))).x;
            v2f  bv = *(const v2f*)((const char*)H + ((p << 7) | ((q ^ p) << 3)));
            float ab2 = bv.x*bv.x + bv.y*bv.y;
            float c_, s_, er, ei;
            if (ab2 > 1e-60f) {
                float abr = __builtin_amdgcn_rsqf(ab2);
                er = bv.x * abr; ei = bv.y * abr;
                float tau = (dv - av) * (0.5f * abr);
                float den = fabsf(tau) + sqrtf(1.f + tau*tau);
                float tv = __builtin_amdgcn_rcpf(den);
                tv = (tau < 0.f) ? -tv : tv;
                c_ = __builtin_amdgcn_rsqf(1.f + tv*tv);
                s_ = tv * c_;
            } else { c_ = 1.f; s_ = 0.f; er = 1.f; ei = 0.f; }
            coefR[t] = make_float4(c_, s_, er, ei);
        }
        __syncthreads();

        const bool chk = (chkcd == 1);

        // my quartet's rows (pair a) and cols (pair b) — pure ALU, no LDS dep
        int r1, r2, c1, c2;
        if (a == 0) { r1 = 15; r2 = rr; }
        else {
            r1 = rr + a;      if (r1 >= 15) r1 -= 15;
            r2 = rr + 15 - a; if (r2 >= 15) r2 -= 15;
        }
        if (b == 0) { c1 = 15; c2 = rr; }
        else {
            c1 = rr + b;      if (c1 >= 15) c1 -= 15;
            c2 = rr + 15 - b; if (c2 >= 15) c2 -= 15;
        }

        const int a11 = (r1 << 7) | ((c1 ^ r1) << 3);
        const int a12 = (r1 << 7) | ((c2 ^ r1) << 3);
        const int a21 = (r2 << 7) | ((c1 ^ r2) << 3);
        const int a22 = (r2 << 7) | ((c2 ^ r2) << 3);
        const int v11 = (va0 << 7) | ((c1 ^ va0) << 3);
        const int v12 = (va0 << 7) | ((c2 ^ va0) << 3);
        const int v21 = (va1 << 7) | ((c1 ^ va1) << 3);
        const int v22 = (va1 << 7) | ((c2 ^ va1) << 3);

        // issue all loads up front (addresses have no LDS dependency)
        v2f h11 = *(const v2f*)((const char*)H + a11);
        v2f h12 = *(const v2f*)((const char*)H + a12);
        v2f h21 = *(const v2f*)((const char*)H + a21);
        v2f h22 = *(const v2f*)((const char*)H + a22);
        v2f q11 = *(const v2f*)((const char*)V + v11);
        v2f q12 = *(const v2f*)((const char*)V + v12);
        v2f q21 = *(const v2f*)((const char*)V + v21);
        v2f q22 = *(const v2f*)((const char*)V + v22);
        float4 fa = coefR[a];
        float4 fb = coefR[b];

        // column coefficients (pair b): cS_p=(cb,0) cO_p=(-sb*ebx, sb*eby)
        //                               cS_q=(cb*ebx,-cb*eby) cO_q=(sb,0)
        const float cb = fb.x, sb = fb.y, ebx = fb.z, eby = fb.w;
        const float sbex = sb*ebx, sbey = sb*eby;
        const float cbex = cb*ebx, cbey = cb*eby;
        const v2f CB  = {cb, cb},      SB  = {sb, sb};
        const v2f P1x = {-sbex,-sbex}, P1y = {-sbey, sbey};
        const v2f Q1x = {cbex, cbex},  Q1y = {cbey,-cbey};

        // row coefficients (pair a), conjugated
        const float ca = fa.x, sa = fa.y, eax = fa.z, eay = fa.w;
        const float saex = sa*eax, saey = sa*eay;
        const float caex = ca*eax, caey = ca*eay;
        const v2f CA  = {ca, ca},      SA  = {sa, sa};
        const v2f P2x = {-saex,-saex}, P2y = {saey,-saey};
        const v2f Q2x = {caex, caex},  Q2y = {-caey, caey};

        // column rotation
        v2f t11 = CB*h11  + P1x*h12 + P1y*vswap(h12);
        v2f t12 = Q1x*h12 + Q1y*vswap(h12) + SB*h11;
        v2f t21 = CB*h21  + P1x*h22 + P1y*vswap(h22);
        v2f t22 = Q1x*h22 + Q1y*vswap(h22) + SB*h21;
        // row rotation
        v2f n11 = CA*t11  + P2x*t21 + P2y*vswap(t21);
        v2f n12 = CA*t12  + P2x*t22 + P2y*vswap(t22);
        v2f n21 = Q2x*t21 + Q2y*vswap(t21) + SA*t11;
        v2f n22 = Q2x*t22 + Q2y*vswap(t22) + SA*t12;
        // V column rotation
        v2f u11 = CB*q11  + P1x*q12 + P1y*vswap(q12);
        v2f u12 = Q1x*q12 + Q1y*vswap(q12) + SB*q11;
        v2f u21 = CB*q21  + P1x*q22 + P1y*vswap(q22);
        v2f u22 = Q1x*q22 + Q1y*vswap(q22) + SB*q21;

        *(v2f*)((char*)H + a11) = n11;
        *(v2f*)((char*)H + a12) = n12;
        *(v2f*)((char*)H + a21) = n21;
        *(v2f*)((char*)H + a22) = n22;
        *(v2f*)((char*)V + v11) = u11;
        *(v2f*)((char*)V + v12) = u12;
        *(v2f*)((char*)V + v21) = u21;
        *(v2f*)((char*)V + v22) = u22;

        float off2 = 0.f;
        if (chk) {
            off2 = n12.x*n12.x + n12.y*n12.y + n21.x*n21.x + n21.y*n21.y;
            if (a != b)
                off2 += n11.x*n11.x + n11.y*n11.y + n22.x*n22.x + n22.y*n22.y;
        }
        __syncthreads();

        rr = (rr == 14) ? 0 : rr + 1;
        ++iter;
        if (chk) {
            #pragma unroll
            for (int m = 1; m < 64; m <<= 1) off2 += __shfl_xor(off2, m);
            if (off2 < tol2 || iter >= MAXROUND) break;
            chkcd = CHKIV;
        } else --chkcd;
    }

    // ---- diag argmin + eigvec extraction ----
    if (t < 16) diagS[t] = H[t << 4].x;
    __syncthreads();
    if (t == 0) {
        float best = diagS[0]; int bi_ = 0;
        for (int m = 1; m < 16; ++m) {
            float vv = diagS[m];
            if (vv < best) { best = vv; bi_ = m; }
        }
        midxS = bi_;
    }
    __syncthreads();
    {
        const int mi = midxS;
        if (t < 16) psiS[t] = V[(t << 4) | (mi ^ t)];
    }
    __syncthreads();

    // ---- loss epilogue (R1-verbatim): lanes 0..31 each handle one d ----
    float contrib = 0.f;
    if (t < 32) {
        float tr = 0.f, ti = 0.f;
        v2f psi[16];
        for (int jj = 0; jj < 16; ++jj) {
            psi[jj] = psiS[jj];
            tr += psi[jj].x; ti += psi[jj].y;
        }
        float zr = 0.f, zi = 0.f, z2r = 0.f, z2i = 0.f;
        for (int jj = 0; jj < 16; ++jj) {
            float2 cj  = cA [t*16 + jj];
            float2 c2j = cA2[t*16 + jj];
            zr  += cj.x*psi[jj].x  - cj.y*psi[jj].y;
            zi  += cj.x*psi[jj].y  + cj.y*psi[jj].x;
            z2r += c2j.x*psi[jj].x - c2j.y*psi[jj].y;
            z2i += c2j.x*psi[jj].y + c2j.y*psi[jj].x;
        }
        float pos = zr*tr + zi*ti;
        float e2  = z2r*tr + z2i*ti;
        float dx  = pos - xS[t];
        contrib = dx*dx + 0.1f*(e2 - pos*pos);
    }
    for (int off = 32; off > 0; off >>= 1)
        contrib += __shfl_down(contrib, off);
    if (t == 0) atomicAdd(out, contrib * (1.0f/(float)NS));
}

extern "C" void kernel_launch(void* const* d_in, const int* in_sizes, int n_in,
                              void* d_out, int out_size, void* d_ws, size_t ws_size,
                              hipStream_t stream)
{
    const float* A_real = (const float*)d_in[0];
    const float* A_imag = (const float*)d_in[1];
    const float* X      = (const float*)d_in[2];
    float* out = (float*)d_out;

    float2* S   = (float2*)d_ws;          // 32*256
    float2* W   = S  + DC*256;            // 32*256
    float2* cA  = W  + DC*256;            // 32*16
    float2* cA2 = cA + DC*16;             // 32*16
    (void)in_sizes; (void)n_in; (void)out_size; (void)ws_size;

    precompute_kernel<<<DC, 256, 0, stream>>>(A_real, A_imag, S, W, cA, cA2, out);
    energy_kernel<<<NS, 64, 0, stream>>>(X, S, W, cA, cA2, out);
}